// Round 1
// baseline (97.373 us; speedup 1.0000x reference)
//
#include <hip/hip_runtime.h>

#define BB 1024
#define DD 512
#define BTILE 64     // batch rows per block
#define JTILE 128    // j columns per block
#define ICH 64       // i depth per block
#define NIC (DD / ICH)              // 8 i-chunks
#define NTP ((DD / JTILE) * NIC)    // 32 t-partial rows per b
#define NNP NIC                     // 8 norm-partial rows per b
#define NROWS (NTP + NNP)           // 40 partial rows
#define XDLD (BTILE + 4)            // 68: +4 pad keeps 16B align, kills store conflicts

// out[b] = ||x_dot[b]||^2 + t[b]^2,  t[b] = sum_{i,j} x_dot[b,i] W[i,j] x[b,j]
//
// Single fused kernel. Block (rg,jc,ic) computes the partial of t[b] over its
// (i,j) rectangle with an 8x4 register tile (32 FMAs per 1KB of LDS W-reads,
// 2x the arithmetic intensity of the previous 4x4 -> LDS pipe drops below the
// VALU floor). jc==0 blocks emit norm partials (values already in registers
// during staging). The LAST of the 32 blocks per batch-group (device-scope
// atomic counter) sums the partials in a fixed order and writes out[] --
// no second kernel launch. Counter triggers on (old&31)==31 so it works on
// poisoned (non-zero) workspace without a memset node, and across graph
// replays (32 consecutive increments always contain exactly one such residue).
__global__ __launch_bounds__(256, 2) void stm_fused_kernel(
    const float* __restrict__ x, const float* __restrict__ xdot,
    const float* __restrict__ W, float* __restrict__ ws,
    float* __restrict__ out) {
  __shared__ float xd_t[ICH][XDLD];   // 17.0 KB transposed x_dot chunk [i][b]
  __shared__ float w_s[ICH][JTILE];   // 32 KB W tile
  __shared__ int last_flag;

  const int tid = threadIdx.x;
  const int b0 = blockIdx.x * BTILE;
  const int j0 = blockIdx.y * JTILE;
  const int i0 = blockIdx.z * ICH;
  const int tb = tid >> 5;   // 0..7  -> rows b0 + 8*tb .. +7
  const int tj = tid & 31;   // 0..31 -> cols j0 + 4*tj .. +3

  unsigned int* cnt = (unsigned int*)(ws + (size_t)NROWS * BB);

  // Stage x_dot chunk transposed: rows b0..b0+63, cols i0..i0+63.
  // 4 consecutive lanes per row (64B contiguous segments, coalesced).
  // Accumulate this thread's 16 squared elements for the norm.
  float nrm = 0.f;
  {
    const int row = tid >> 2;            // 0..63
    const int q = tid & 3;               // 0..3
    const float4* src = (const float4*)(xdot + (size_t)(b0 + row) * DD + i0);
#pragma unroll
    for (int p = 0; p < 4; ++p) {
      const int c4 = q + p * 4;          // 0..15
      float4 v = src[c4];
      nrm += v.x * v.x + v.y * v.y + v.z * v.z + v.w * v.w;
      const int c = c4 * 4;
      xd_t[c + 0][row] = v.x; xd_t[c + 1][row] = v.y;
      xd_t[c + 2][row] = v.z; xd_t[c + 3][row] = v.w;
    }
  }
  // Stage W tile: rows i0..i0+63, cols j0..j0+127 (2048 float4 / 256 thr).
  {
#pragma unroll
    for (int v = 0; v < 8; ++v) {
      const int f4 = tid + v * 256;
      const int ii = f4 >> 5, jj4 = f4 & 31;
      *((float4*)&w_s[ii][jj4 * 4]) =
          ((const float4*)(W + (size_t)(i0 + ii) * DD + j0))[jj4];
    }
  }

  // Norm partials: row r's 4 stagers are consecutive lanes 4r..4r+3 (same
  // wave) -> two xor folds, lane 4r holds the row total. Only jc==0 blocks.
  if (blockIdx.y == 0) {
    nrm += __shfl_xor(nrm, 1);
    nrm += __shfl_xor(nrm, 2);
    if ((tid & 3) == 0)
      ws[(size_t)(NTP + blockIdx.z) * BB + b0 + (tid >> 2)] = nrm;
  }

  // Prefetch epilogue x values so their latency overlaps the FMA loop.
  float4 xv[8];
#pragma unroll
  for (int r = 0; r < 8; ++r)
    xv[r] = ((const float4*)(x + (size_t)(b0 + tb * 8 + r) * DD + j0))[tj];

  __syncthreads();

  // acc[r][c] = sum_i xd[b0+8tb+r, i] * W[i, j0+4tj+c]
  float acc[8][4] = {};
#pragma unroll
  for (int i = 0; i < ICH; ++i) {
    const float4 xa = *(const float4*)&xd_t[i][tb * 8];      // broadcast reads
    const float4 xb = *(const float4*)&xd_t[i][tb * 8 + 4];  // (2 addrs/wave)
    const float4 w  = *(const float4*)&w_s[i][tj * 4];       // 1KB/wave, conflict-free
    const float xr[8] = {xa.x, xa.y, xa.z, xa.w, xb.x, xb.y, xb.z, xb.w};
#pragma unroll
    for (int r = 0; r < 8; ++r) {
      acc[r][0] += xr[r] * w.x; acc[r][1] += xr[r] * w.y;
      acc[r][2] += xr[r] * w.z; acc[r][3] += xr[r] * w.w;
    }
  }

  // Contract with prefetched x, reduce over the 32 tj lanes.
  float tp[8];
#pragma unroll
  for (int r = 0; r < 8; ++r)
    tp[r] = acc[r][0] * xv[r].x + acc[r][1] * xv[r].y +
            acc[r][2] * xv[r].z + acc[r][3] * xv[r].w;
#pragma unroll
  for (int off = 16; off >= 1; off >>= 1) {
#pragma unroll
    for (int r = 0; r < 8; ++r) tp[r] += __shfl_xor(tp[r], off);
  }
  if (tj == 0) {
    const int p = blockIdx.y * NIC + blockIdx.z;   // 0..31
    float* dst = ws + (size_t)p * BB + b0 + tb * 8;
    *(float4*)(dst + 0) = make_float4(tp[0], tp[1], tp[2], tp[3]);
    *(float4*)(dst + 4) = make_float4(tp[4], tp[5], tp[6], tp[7]);
  }

  // ---- fused finalize: last of the 32 (y,z) blocks for this batch group ----
  __threadfence();              // release: partials visible device-wide
  __syncthreads();              // all threads' stores fenced
  if (tid == 0) {
    unsigned int old = atomicAdd(cnt + blockIdx.x, 1u);
    last_flag = ((old & 31u) == 31u);   // poison-start & replay safe
  }
  __syncthreads();
  if (last_flag) {
    __threadfence();            // acquire: see other XCDs' partials
    const int bl = tid & 63, g = tid >> 6;         // 4 waves x 64 rows
    float ts = 0.f, ns = 0.f;
#pragma unroll
    for (int k = 0; k < 8; ++k)
      ts += ws[(size_t)(g * 8 + k) * BB + b0 + bl];
#pragma unroll
    for (int k = 0; k < 2; ++k)
      ns += ws[(size_t)(NTP + g * 2 + k) * BB + b0 + bl];
    float* red = (float*)xd_t;  // reuse LDS (all compute done)
    red[g * 64 + bl] = ts;
    red[256 + g * 64 + bl] = ns;
    __syncthreads();
    if (tid < 64) {
      const float t = red[tid] + red[64 + tid] + red[128 + tid] + red[192 + tid];
      const float n = red[256 + tid] + red[320 + tid] + red[384 + tid] + red[448 + tid];
      out[b0 + tid] = n + t * t;  // fixed order -> deterministic
    }
  }
}

extern "C" void kernel_launch(void* const* d_in, const int* in_sizes, int n_in,
                              void* d_out, int out_size, void* d_ws, size_t ws_size,
                              hipStream_t stream) {
  const float* x    = (const float*)d_in[0];
  const float* xdot = (const float*)d_in[1];
  const float* W    = (const float*)d_in[2];
  float* ws = (float*)d_ws;   // 40*1024 floats of partials + 16 uint counters
  float* out = (float*)d_out;

  dim3 g1(BB / BTILE, DD / JTILE, NIC);  // (16, 4, 8) = 512 blocks
  stm_fused_kernel<<<g1, 256, 0, stream>>>(x, xdot, W, ws, out);
}

// Round 2
// 68.655 us; speedup vs baseline: 1.4183x; 1.4183x over previous
//
#include <hip/hip_runtime.h>

#define BB 1024
#define DD 512
#define BTILE 64     // batch rows per block
#define JTILE 128    // j columns per block
#define ICH 32       // i depth per block (halved: smaller LDS, 4 blocks/CU)
#define NIC (DD / ICH)              // 16 i-chunks
#define NJC (DD / JTILE)            // 4 j-chunks
#define NTP (NJC * NIC)             // 64 t-partial rows per b
#define NNP NIC                     // 16 norm-partial rows per b
#define NROWS (NTP + NNP)           // 80 partial rows (320 KB, L2-resident)
#define XDLD (BTILE + 4)            // 68: keeps 16B align, tolerable store conflicts

// out[b] = ||x_dot[b]||^2 + t[b]^2,  t[b] = sum_{i,j} x_dot[b,i] W[i,j] x[b,j]
//
// k1: block (rg,jc,ic) computes the partial of t[b] over its (i,j) rectangle
//     with an 8x4 register tile (32 FMA-instr per ~20 LDS-cyc -> VALU-bound
//     at the pipe level). LDS = 16KB W + 8.5KB xd = ~25KB -> 4 blocks/CU
//     resident (vs round-1's 2). NO device fences / atomics: round 1 showed
//     agent-scope __threadfence() in every block costs ~20+ us in serialized
//     L2 writebacks on non-coherent per-XCD L2s. Kernel boundary is free.
// k2: trivial per-b finalize over 80 L2-resident partial rows.
__global__ __launch_bounds__(256, 4) void stm_main_kernel(
    const float* __restrict__ x, const float* __restrict__ xdot,
    const float* __restrict__ W, float* __restrict__ ws) {
  __shared__ float xd_t[ICH][XDLD];   // 8.5 KB transposed x_dot chunk [i][b]
  __shared__ float w_s[ICH][JTILE];   // 16 KB W tile

  const int tid = threadIdx.x;
  const int b0 = blockIdx.x * BTILE;
  const int j0 = blockIdx.y * JTILE;
  const int i0 = blockIdx.z * ICH;
  const int tb = tid >> 5;   // 0..7  -> rows b0 + 8*tb .. +7
  const int tj = tid & 31;   // 0..31 -> cols j0 + 4*tj .. +3

  // Stage x_dot chunk transposed: rows b0..b0+63, cols i0..i0+31.
  // 8 consecutive lanes per row (128B contiguous segments, coalesced).
  // Each thread covers one float4 of rowA (0..31) and one of rowB (32..63);
  // accumulate the squares for the norm while the values are in registers.
  float nA = 0.f, nB = 0.f;
  {
    const int q = tid & 7;               // float4 col within the 32-wide chunk
    const int rowA = tid >> 3;           // 0..31
    const int rowB = rowA + 32;          // 32..63
    const float4 va = ((const float4*)(xdot + (size_t)(b0 + rowA) * DD + i0))[q];
    const float4 vb = ((const float4*)(xdot + (size_t)(b0 + rowB) * DD + i0))[q];
    nA = va.x * va.x + va.y * va.y + va.z * va.z + va.w * va.w;
    nB = vb.x * vb.x + vb.y * vb.y + vb.z * vb.z + vb.w * vb.w;
    const int c = q * 4;
    xd_t[c + 0][rowA] = va.x; xd_t[c + 1][rowA] = va.y;
    xd_t[c + 2][rowA] = va.z; xd_t[c + 3][rowA] = va.w;
    xd_t[c + 0][rowB] = vb.x; xd_t[c + 1][rowB] = vb.y;
    xd_t[c + 2][rowB] = vb.z; xd_t[c + 3][rowB] = vb.w;
  }
  // Stage W tile: rows i0..i0+31, cols j0..j0+127 (1024 float4 / 256 thr).
  {
#pragma unroll
    for (int v = 0; v < 4; ++v) {
      const int f4 = tid + v * 256;
      const int ii = f4 >> 5, jj4 = f4 & 31;
      *((float4*)&w_s[ii][jj4 * 4]) =
          ((const float4*)(W + (size_t)(i0 + ii) * DD + j0))[jj4];
    }
  }

  // Norm partials: a row's 8 stagers are consecutive lanes 8r..8r+7 (same
  // wave) -> three xor folds; lane 8r holds the row totals. Only jc==0.
  if (blockIdx.y == 0) {
    nA += __shfl_xor(nA, 1); nA += __shfl_xor(nA, 2); nA += __shfl_xor(nA, 4);
    nB += __shfl_xor(nB, 1); nB += __shfl_xor(nB, 2); nB += __shfl_xor(nB, 4);
    if ((tid & 7) == 0) {
      float* nr = ws + (size_t)(NTP + blockIdx.z) * BB + b0;
      nr[(tid >> 3)] = nA;
      nr[32 + (tid >> 3)] = nB;
    }
  }

  // Prefetch epilogue x values so their latency overlaps the FMA loop.
  float4 xv[8];
#pragma unroll
  for (int r = 0; r < 8; ++r)
    xv[r] = ((const float4*)(x + (size_t)(b0 + tb * 8 + r) * DD + j0))[tj];

  __syncthreads();

  // acc[r][c] = sum_i xd[b0+8tb+r, i] * W[i, j0+4tj+c]
  float acc[8][4] = {};
#pragma unroll
  for (int i = 0; i < ICH; ++i) {
    const float4 xa = *(const float4*)&xd_t[i][tb * 8];      // broadcast reads
    const float4 xb = *(const float4*)&xd_t[i][tb * 8 + 4];  // (2 addrs/wave)
    const float4 w  = *(const float4*)&w_s[i][tj * 4];       // dense row read
    const float xr[8] = {xa.x, xa.y, xa.z, xa.w, xb.x, xb.y, xb.z, xb.w};
#pragma unroll
    for (int r = 0; r < 8; ++r) {
      acc[r][0] += xr[r] * w.x; acc[r][1] += xr[r] * w.y;
      acc[r][2] += xr[r] * w.z; acc[r][3] += xr[r] * w.w;
    }
  }

  // Contract with prefetched x, reduce over the 32 tj lanes.
  float tp[8];
#pragma unroll
  for (int r = 0; r < 8; ++r)
    tp[r] = acc[r][0] * xv[r].x + acc[r][1] * xv[r].y +
            acc[r][2] * xv[r].z + acc[r][3] * xv[r].w;
#pragma unroll
  for (int off = 16; off >= 1; off >>= 1) {
#pragma unroll
    for (int r = 0; r < 8; ++r) tp[r] += __shfl_xor(tp[r], off);
  }
  if (tj == 0) {
    const int p = blockIdx.y * NIC + blockIdx.z;   // 0..63
    float* dst = ws + (size_t)p * BB + b0 + tb * 8;
    *(float4*)(dst + 0) = make_float4(tp[0], tp[1], tp[2], tp[3]);
    *(float4*)(dst + 4) = make_float4(tp[4], tp[5], tp[6], tp[7]);
  }
}

// k2: one thread per b. out[b] = (sum norm partials) + (sum t partials)^2.
// 320 KB of partials, L2-resident, fully coalesced across b. Fixed order.
__global__ __launch_bounds__(256) void stm_final_kernel(
    const float* __restrict__ ws, float* __restrict__ out) {
  const int b = blockIdx.x * 256 + threadIdx.x;
  float t = 0.f, n = 0.f;
#pragma unroll
  for (int p = 0; p < NTP; ++p) t += ws[(size_t)p * BB + b];
#pragma unroll
  for (int p = 0; p < NNP; ++p) n += ws[(size_t)(NTP + p) * BB + b];
  out[b] = n + t * t;
}

extern "C" void kernel_launch(void* const* d_in, const int* in_sizes, int n_in,
                              void* d_out, int out_size, void* d_ws, size_t ws_size,
                              hipStream_t stream) {
  const float* x    = (const float*)d_in[0];
  const float* xdot = (const float*)d_in[1];
  const float* W    = (const float*)d_in[2];
  float* ws = (float*)d_ws;   // 80 * 1024 floats = 320 KB of partials
  float* out = (float*)d_out;

  dim3 g1(BB / BTILE, DD / JTILE, NIC);  // (16, 4, 16) = 1024 blocks, 4/CU
  stm_main_kernel<<<g1, 256, 0, stream>>>(x, xdot, W, ws);
  stm_final_kernel<<<BB / 256, 256, 0, stream>>>(ws, out);
}